// Round 5
// baseline (380.777 us; speedup 1.0000x reference)
//
#include <hip/hip_runtime.h>
#include <hip/hip_bf16.h>
#include <math.h>

#define NNODES 4096
#define NCOLS  96          // B*T
#define NROWS  12288       // K*NNODES
#define KSEG   16          // K-split ways
#define KLEN   (NNODES / KSEG)   // 256

typedef __attribute__((ext_vector_type(8))) short short8;
typedef __attribute__((ext_vector_type(4))) float float4v;

// ---------------------------------------------------------------------------
// Inline dtype probe: 1 => fp32 inputs, 0 => bf16. Wave-uniform (all waves
// read the same 64 words of adj -> identical ballot). Validated fp32 on this
// harness; logic: buffer insane-as-bf16 => it's fp32.
// ---------------------------------------------------------------------------
__device__ __forceinline__ int probe32(const void* adjp) {
    const unsigned* aw = (const unsigned*)adjp;
    unsigned w = aw[threadIdx.x & 63];
    unsigned e = (w >> 7) & 0xffu;
    bool insane = (e >= 0xC0u) || (e <= 0x30u);
    unsigned long long m = __ballot(insane);
    return (__popcll(m) >= 16) ? 1 : 0;
}

__device__ __forceinline__ float ldf(const void* p, size_t i, int isf32) {
    return isf32 ? ((const float*)p)[i]
                 : __bfloat162float(((const __hip_bfloat16*)p)[i]);
}

__device__ __forceinline__ void ld8(float* d, const void* p, size_t e, int isf32) {
    if (isf32) {
        const float4* s = (const float4*)((const float*)p + e);
        float4 f0 = s[0], f1 = s[1];
        d[0] = f0.x; d[1] = f0.y; d[2] = f0.z; d[3] = f0.w;
        d[4] = f1.x; d[5] = f1.y; d[6] = f1.z; d[7] = f1.w;
    } else {
        const __hip_bfloat16* s = (const __hip_bfloat16*)p + e;
#pragma unroll
        for (int j = 0; j < 8; j++) d[j] = __bfloat162float(s[j]);
    }
}

// pack 8 fp32 -> short8 of bf16 (RNE via __float2bfloat16)
__device__ __forceinline__ short8 cvt8(float4 a, float4 b) {
    union { short8 v; __hip_bfloat16 h[8]; } u;
    u.h[0] = __float2bfloat16(a.x); u.h[1] = __float2bfloat16(a.y);
    u.h[2] = __float2bfloat16(a.z); u.h[3] = __float2bfloat16(a.w);
    u.h[4] = __float2bfloat16(b.x); u.h[5] = __float2bfloat16(b.y);
    u.h[6] = __float2bfloat16(b.z); u.h[7] = __float2bfloat16(b.w);
    return u.v;
}

// ---------------------------------------------------------------------------
// Kernel 0: convert X (96 x 4096) to bf16 in workspace (once; L2/L3-resident
// thereafter). 192 blocks x 256 thr x 8 elems.
// ---------------------------------------------------------------------------
__global__ __launch_bounds__(256) void cvt_x(
    const void* __restrict__ xv, __hip_bfloat16* __restrict__ xbf,
    const void* __restrict__ adjp)
{
    const int isf32 = probe32(adjp);
    const int i = (blockIdx.x * 256 + threadIdx.x) * 8;
    if (isf32) {
        const float* xf = (const float*)xv;
        float4 f0 = *(const float4*)(xf + i);
        float4 f1 = *(const float4*)(xf + i + 4);
        short8 v = cvt8(f0, f1);
        *(short8*)(xbf + i) = v;
    } else {
        *(uint4*)(xbf + i) = *(const uint4*)((const __hip_bfloat16*)xv + i);
    }
}

// ---------------------------------------------------------------------------
// Kernel 1 (v5): y = adj @ X^T, bf16 MFMA 16x16x32. BARRIER-FREE K-loop.
// KSEG=16: per-block X slice = 96 rows x 256 k bf16 = 48 KB -> fits LDS
// whole. Stage once (single __syncthreads), then the K-loop has NO sync:
// adj streams global->reg (2-deep, fully static), X fragments from read-only
// swizzled LDS (chunk' = c ^ (row&7), conflict-free ds_read_b128).
// v5: first two adj prefetch loads hoisted ABOVE the barrier so the adj
// stream overlaps the staging drain.
// Grid 96 rowgroups x 16 ksegs = 1536 blocks x 512 thr; 48 KB LDS.
// Output: yws slice ks; C/D mapping P0: col=lane&15, row=(lane>>4)*4+reg.
// ---------------------------------------------------------------------------
__global__ __launch_bounds__(512, 4) void gemm_y(
    const void* __restrict__ adjv, const __hip_bfloat16* __restrict__ xbf,
    float* __restrict__ yws)
{
    __shared__ uint4 Xs[96 * 32];   // 48 KB, swizzled 16B chunks

    const int tid = threadIdx.x;
    const int isf32 = probe32(adjv);
    const int wv = tid >> 6, ln = tid & 63, fr = ln & 15, fq = ln >> 4;

    const int bid = blockIdx.x;
    const int rt0 = (bid >> 4) * 128;   // 128 rows per block (8 waves x 16)
    const int ks  = bid & 15;
    const int k0  = ks * KLEN;

    // ---- stage X slice: 96*32 = 3072 chunks of 16B, 6 per thread ----
#pragma unroll
    for (int s = 0; s < 6; s++) {
        int L = tid + s * 512;
        int r = L >> 5, c = L & 31;
        Xs[r * 32 + (c ^ (r & 7))] =
            *(const uint4*)(xbf + (size_t)r * NNODES + k0 + c * 8);
    }

    float4v acc[6];
#pragma unroll
    for (int i = 0; i < 6; i++) acc[i] = (float4v){0.f, 0.f, 0.f, 0.f};

    const int arow = rt0 + wv * 16 + fr;   // this lane's adj row

#define XFRAG(CT, STEP) \
    (*(const short8*)&Xs[((CT) * 16 + fr) * 32 + ((((STEP) * 4) + fq) ^ (((CT) * 16 + fr) & 7))])

    if (isf32) {
        const float* ap = (const float*)adjv + (size_t)arow * NNODES + k0 + fq * 8;
        float4 AA[2], AB[2];

#define ALOADF(R, STEP) { const float* p = ap + (STEP) * 32;                   \
        R[0] = *(const float4*)p; R[1] = *(const float4*)(p + 4); }
#define COMPF(R, STEP) { short8 a = cvt8(R[0], R[1]);                          \
        _Pragma("unroll")                                                      \
        for (int ct = 0; ct < 6; ct++)                                         \
            acc[ct] = __builtin_amdgcn_mfma_f32_16x16x32_bf16(a, XFRAG(ct, STEP), acc[ct], 0, 0, 0); }

        ALOADF(AA, 0); ALOADF(AB, 1);      // in flight during barrier wait
        __syncthreads();                   // the ONLY barrier
        COMPF(AA, 0);  ALOADF(AA, 2);
        COMPF(AB, 1);  ALOADF(AB, 3);
        COMPF(AA, 2);  ALOADF(AA, 4);
        COMPF(AB, 3);  ALOADF(AB, 5);
        COMPF(AA, 4);  ALOADF(AA, 6);
        COMPF(AB, 5);  ALOADF(AB, 7);
        COMPF(AA, 6);
        COMPF(AB, 7);
#undef ALOADF
#undef COMPF
    } else {
        // bf16 adj path (insurance): one uint4 per 32-k fragment
        const __hip_bfloat16* ap = (const __hip_bfloat16*)adjv + (size_t)arow * NNODES + k0 + fq * 8;
        uint4 AA, AB;

#define ALOADB(R, STEP) R = *(const uint4*)(ap + (STEP) * 32);
#define COMPB(R, STEP) { short8 a = *(const short8*)&R;                        \
        _Pragma("unroll")                                                      \
        for (int ct = 0; ct < 6; ct++)                                         \
            acc[ct] = __builtin_amdgcn_mfma_f32_16x16x32_bf16(a, XFRAG(ct, STEP), acc[ct], 0, 0, 0); }

        ALOADB(AA, 0); ALOADB(AB, 1);
        __syncthreads();
        COMPB(AA, 0);  ALOADB(AA, 2);
        COMPB(AB, 1);  ALOADB(AB, 3);
        COMPB(AA, 2);  ALOADB(AA, 4);
        COMPB(AB, 3);  ALOADB(AB, 5);
        COMPB(AA, 4);  ALOADB(AA, 6);
        COMPB(AB, 5);  ALOADB(AB, 7);
        COMPB(AA, 6);
        COMPB(AB, 7);
#undef ALOADB
#undef COMPB
    }
#undef XFRAG

    // store partials: slice ks, P0 mapping
    float* yo = yws + (size_t)ks * NROWS * NCOLS;
#pragma unroll
    for (int ct = 0; ct < 6; ct++)
#pragma unroll
        for (int rg = 0; rg < 4; rg++) {
            size_t r = (size_t)rt0 + wv * 16 + fq * 4 + rg;
            yo[r * NCOLS + ct * 16 + fr] = acc[ct][rg];
        }
}

// ---------------------------------------------------------------------------
// Kernel 1b: streaming reduction of the KSEG partial slices into slice 0.
// Fully-coalesced float4 per thread per slice; 75 MB read (mostly L3) +
// 4.7 MB write. 1152 blocks x 256 thr x 1 float4.
// ---------------------------------------------------------------------------
__global__ __launch_bounds__(256) void reduce_y(float* __restrict__ yws)
{
    const size_t i = ((size_t)blockIdx.x * 256 + threadIdx.x) * 4;
    float4 s = *(const float4*)(yws + i);
#pragma unroll
    for (int sl = 1; sl < KSEG; sl++) {
        const float4 v = *(const float4*)(yws + (size_t)sl * NROWS * NCOLS + i);
        s.x += v.x; s.y += v.y; s.z += v.z; s.w += v.w;
    }
    *(float4*)(yws + i) = s;
}

// ---------------------------------------------------------------------------
// Kernel 2: epilogue. 4 lanes (a quad) per (b,n): each lane owns 3 t's of the
// cheb/sgc sum, quad-reduced via shfl_xor; GLU o-range split across the quad.
// Reads the single reduced slice. j-loop uses float4 LDS reads (4x b128/j
// instead of 15x b32/j). 512 blocks x 256 thr.
// yws layout [k*4096+n][b*12+t].
// ---------------------------------------------------------------------------
__global__ __launch_bounds__(256) void epilogue_kernel(
    const void* __restrict__ xv, const float* __restrict__ yws,
    const void* __restrict__ chebv, const void* __restrict__ gcnwv,
    const void* __restrict__ gcnbv, const void* __restrict__ g1wv,
    const void* __restrict__ g1bv, const void* __restrict__ g2wv,
    const void* __restrict__ g2bv,
    float* __restrict__ out, const void* __restrict__ adjp)
{
    __shared__ __align__(16) float gwL[9216];   // [t][j*12+o], 48B rows -> f4 ok
    __shared__ __align__(16) float cw4L[256];   // [j*4+k], padded to float4
    __shared__ float w1L[216];    // [o*18 + c*3 + kh]  (kw=1 tap)
    __shared__ float w2L[216];
    __shared__ float wbL[36];

    const int tid = threadIdx.x;
    const int isf32 = probe32(adjp);

    for (int i = tid; i < 9216; i += 256) {
        int o = i / 768, t = (i / 64) % 12, j = i % 64;   // gcn_w flat (o,t,0,j)
        gwL[t * 768 + j * 12 + o] = ldf(gcnwv, i, isf32);
    }
    if (tid < 256) {
        int j = tid >> 2, kk = tid & 3;
        cw4L[tid] = (kk < 3 && j < 64) ? ldf(chebv, j * 3 + kk, isf32) : 0.f;
    }
    if (tid < 216) {
        w1L[tid] = ldf(g1wv, (size_t)tid * 3 + 1, isf32);
        w2L[tid] = ldf(g2wv, (size_t)tid * 3 + 1, isf32);
    }
    if (tid < 12) {
        wbL[tid]      = ldf(gcnbv, tid, isf32);
        wbL[12 + tid] = ldf(g1bv, tid, isf32);
        wbL[24 + tid] = ldf(g2bv, tid, isf32);
    }
    __syncthreads();

    const int gid = blockIdx.x * 256 + tid;   // 0..131071
    const int pr  = gid >> 2;                 // (b,n) pair 0..32767
    const int tq  = gid & 3;                  // t-quarter 0..3
    const int b = pr >> 12;
    const int n = pr & (NNODES - 1);

    // y values for this lane's 3 t's (single reduced slice)
    float yk[3][3];
#pragma unroll
    for (int k = 0; k < 3; k++) {
        const float* yp = yws + ((size_t)(k * NNODES + n)) * NCOLS + b * 12 + tq * 3;
        yk[k][0] = yp[0]; yk[k][1] = yp[1]; yk[k][2] = yp[2];
    }

    // ---- cheb -> relu -> partial sgc over 3 t's ----
    float sg[12];
#pragma unroll
    for (int o = 0; o < 12; o++) sg[o] = 0.f;
    const float4* cw4 = (const float4*)cw4L;
#pragma unroll
    for (int i = 0; i < 3; i++) {
        const float y0 = yk[0][i], y1 = yk[1][i], y2 = yk[2][i];
        const float4* gw4 = (const float4*)(gwL + (tq * 3 + i) * 768);
#pragma unroll 4
        for (int j = 0; j < 64; j++) {
            float4 cw = cw4[j];
            float h = fmaf(y0, cw.x, fmaf(y1, cw.y, y2 * cw.z));
            h = fmaxf(h, 0.f);
            float4 g0 = gw4[j * 3], g1 = gw4[j * 3 + 1], g2 = gw4[j * 3 + 2];
            sg[0] += h * g0.x; sg[1] += h * g0.y; sg[2]  += h * g0.z; sg[3]  += h * g0.w;
            sg[4] += h * g1.x; sg[5] += h * g1.y; sg[6]  += h * g1.z; sg[7]  += h * g1.w;
            sg[8] += h * g2.x; sg[9] += h * g2.y; sg[10] += h * g2.z; sg[11] += h * g2.w;
        }
    }
    // quad reduction: all 4 lanes end with the full t-sum
#pragma unroll
    for (int o = 0; o < 12; o++) {
        sg[o] += __shfl_xor(sg[o], 1);
        sg[o] += __shfl_xor(sg[o], 2);
    }

    // ---- GLU (dilated conv taps n-2, n, n+2; only kw=1 alive); this lane
    // handles o = tq*3 .. tq*3+2 ----
    float xa[18], xg[18];
#pragma unroll
    for (int c = 0; c < 6; c++)
#pragma unroll
        for (int kh = 0; kh < 3; kh++) {
            int m = n + 2 * kh - 2;
            bool ok = ((unsigned)m < (unsigned)NNODES);
            xa[c * 3 + kh] = ok ? ldf(xv, ((size_t)(b * 12 + c)) * NNODES + m, isf32) : 0.f;
            xg[c * 3 + kh] = ok ? ldf(xv, ((size_t)(b * 12 + c + 6)) * NNODES + m, isf32) : 0.f;
        }

#pragma unroll
    for (int i = 0; i < 3; i++) {
        const int o = tq * 3 + i;
        float av = wbL[12 + o], gv = wbL[24 + o];
#pragma unroll
        for (int q = 0; q < 18; q++) {
            av += xa[q] * w1L[o * 18 + q];
            gv += xg[q] * w2L[o * 18 + q];
        }
        float s = 1.f / (1.f + expf(-gv));
        out[((size_t)(b * 12 + o)) * NNODES + n] = av * s + sg[o] + wbL[o];
    }
}

// ---------------------------------------------------------------------------
// Fallback single kernel (only if ws too small): verified path.
// ---------------------------------------------------------------------------
__global__ __launch_bounds__(64) void fused_simple(
    const void* __restrict__ xv, const void* __restrict__ adjv,
    const void* __restrict__ chebv, const void* __restrict__ gcnwv,
    const void* __restrict__ gcnbv, const void* __restrict__ g1wv,
    const void* __restrict__ g1bv, const void* __restrict__ g2wv,
    const void* __restrict__ g2bv,
    float* __restrict__ out)
{
    __shared__ float gwL[9216];
    __shared__ float cwL[192];
    __shared__ float w1L[216];
    __shared__ float w2L[216];
    __shared__ float wbL[36];

    const int tid = threadIdx.x;
    const int isf32 = probe32(adjv);

    for (int i = tid; i < 9216; i += 64) {
        int o = i / 768, t = (i / 64) % 12, j = i % 64;
        gwL[t * 768 + j * 12 + o] = ldf(gcnwv, i, isf32);
    }
    for (int i = tid; i < 192; i += 64) cwL[i] = ldf(chebv, i, isf32);
    for (int i = tid; i < 216; i += 64) {
        w1L[i] = ldf(g1wv, (size_t)i * 3 + 1, isf32);
        w2L[i] = ldf(g2wv, (size_t)i * 3 + 1, isf32);
    }
    if (tid < 12) {
        wbL[tid]      = ldf(gcnbv, tid, isf32);
        wbL[12 + tid] = ldf(g1bv, tid, isf32);
        wbL[24 + tid] = ldf(g2bv, tid, isf32);
    }
    __syncthreads();

    const int g = blockIdx.x * 64 + tid;
    const int b = g >> 12;
    const int n = g & (NNODES - 1);

    float y[3][12];
#pragma unroll
    for (int k = 0; k < 3; k++)
#pragma unroll
        for (int t = 0; t < 12; t++) y[k][t] = 0.f;

    for (int m0 = 0; m0 < NNODES; m0 += 8) {
        float a0[8], a1[8], a2[8];
        ld8(a0, adjv, ((size_t)(0 * NNODES + n)) * NNODES + m0, isf32);
        ld8(a1, adjv, ((size_t)(1 * NNODES + n)) * NNODES + m0, isf32);
        ld8(a2, adjv, ((size_t)(2 * NNODES + n)) * NNODES + m0, isf32);
#pragma unroll
        for (int t = 0; t < 12; t++) {
            float x8[8];
            ld8(x8, xv, ((size_t)(b * 12 + t)) * NNODES + m0, isf32);
#pragma unroll
            for (int j = 0; j < 8; j++) {
                y[0][t] += a0[j] * x8[j];
                y[1][t] += a1[j] * x8[j];
                y[2][t] += a2[j] * x8[j];
            }
        }
    }

    float sg[12];
#pragma unroll
    for (int o = 0; o < 12; o++) sg[o] = wbL[o];
    for (int t = 0; t < 12; t++) {
        const float y0 = y[0][t], y1 = y[1][t], y2 = y[2][t];
        const float* gwt = gwL + t * 768;
#pragma unroll 4
        for (int j = 0; j < 64; j++) {
            float h = y0 * cwL[j * 3] + y1 * cwL[j * 3 + 1] + y2 * cwL[j * 3 + 2];
            h = fmaxf(h, 0.f);
#pragma unroll
            for (int o = 0; o < 12; o++) sg[o] += h * gwt[j * 12 + o];
        }
    }

    float xa[18], xg[18];
#pragma unroll
    for (int c = 0; c < 6; c++)
#pragma unroll
        for (int kh = 0; kh < 3; kh++) {
            int m = n + 2 * kh - 2;
            bool ok = ((unsigned)m < (unsigned)NNODES);
            xa[c * 3 + kh] = ok ? ldf(xv, ((size_t)(b * 12 + c)) * NNODES + m, isf32) : 0.f;
            xg[c * 3 + kh] = ok ? ldf(xv, ((size_t)(b * 12 + c + 6)) * NNODES + m, isf32) : 0.f;
        }

#pragma unroll
    for (int o = 0; o < 12; o++) {
        float av = wbL[12 + o], gv = wbL[24 + o];
#pragma unroll
        for (int i = 0; i < 18; i++) {
            av += xa[i] * w1L[o * 18 + i];
            gv += xg[i] * w2L[o * 18 + i];
        }
        float s = 1.f / (1.f + expf(-gv));
        out[((size_t)(b * 12 + o)) * NNODES + n] = av * s + sg[o];
    }
}

// ---------------------------------------------------------------------------
extern "C" void kernel_launch(void* const* d_in, const int* in_sizes, int n_in,
                              void* d_out, int out_size, void* d_ws, size_t ws_size,
                              hipStream_t stream)
{
    __hip_bfloat16* xbf = (__hip_bfloat16*)((char*)d_ws + 64);      // 768 KB
    float* yws = (float*)((char*)d_ws + 64 + (size_t)NCOLS * NNODES * 2);
    const size_t need = 64 + (size_t)NCOLS * NNODES * 2
                      + (size_t)KSEG * NROWS * NCOLS * 4;

    if (ws_size >= need) {
        hipLaunchKernelGGL(cvt_x, dim3(192), dim3(256), 0, stream,
                           d_in[0], xbf, d_in[1]);
        hipLaunchKernelGGL(gemm_y, dim3(96 * KSEG), dim3(512), 0, stream,
                           d_in[1], xbf, yws);
        hipLaunchKernelGGL(reduce_y, dim3(NROWS * NCOLS / 1024), dim3(256), 0, stream,
                           yws);
        hipLaunchKernelGGL(epilogue_kernel, dim3(512), dim3(256), 0, stream,
                           d_in[0], yws, d_in[2], d_in[3], d_in[4],
                           d_in[5], d_in[6], d_in[7], d_in[8],
                           (float*)d_out, d_in[1]);
    } else {
        hipLaunchKernelGGL(fused_simple, dim3(512), dim3(64), 0, stream,
                           d_in[0], d_in[1], d_in[2], d_in[3], d_in[4],
                           d_in[5], d_in[6], d_in[7], d_in[8],
                           (float*)d_out);
    }
}

// Round 6
// 345.374 us; speedup vs baseline: 1.1025x; 1.1025x over previous
//
#include <hip/hip_runtime.h>
#include <hip/hip_bf16.h>
#include <math.h>

#define NNODES 4096
#define NCOLS  96          // B*T
#define NROWS  12288       // K*NNODES
#define KSEG   8           // K-split ways (8 partial slices)
#define KLEN   (NNODES / KSEG)       // 512 k per block, two 256-k LDS stages
#define YSLICE ((size_t)NROWS * NCOLS)

typedef __attribute__((ext_vector_type(8))) short short8;
typedef __attribute__((ext_vector_type(4))) float float4v;

// ---------------------------------------------------------------------------
// Inline dtype probe: 1 => fp32 inputs, 0 => bf16. Wave-uniform ballot on the
// same 64 words of adj. Validated fp32 on this harness.
// ---------------------------------------------------------------------------
__device__ __forceinline__ int probe32(const void* adjp) {
    const unsigned* aw = (const unsigned*)adjp;
    unsigned w = aw[threadIdx.x & 63];
    unsigned e = (w >> 7) & 0xffu;
    bool insane = (e >= 0xC0u) || (e <= 0x30u);
    unsigned long long m = __ballot(insane);
    return (__popcll(m) >= 16) ? 1 : 0;
}

__device__ __forceinline__ float ldf(const void* p, size_t i, int isf32) {
    return isf32 ? ((const float*)p)[i]
                 : __bfloat162float(((const __hip_bfloat16*)p)[i]);
}

__device__ __forceinline__ void ld8(float* d, const void* p, size_t e, int isf32) {
    if (isf32) {
        const float4* s = (const float4*)((const float*)p + e);
        float4 f0 = s[0], f1 = s[1];
        d[0] = f0.x; d[1] = f0.y; d[2] = f0.z; d[3] = f0.w;
        d[4] = f1.x; d[5] = f1.y; d[6] = f1.z; d[7] = f1.w;
    } else {
        const __hip_bfloat16* s = (const __hip_bfloat16*)p + e;
#pragma unroll
        for (int j = 0; j < 8; j++) d[j] = __bfloat162float(s[j]);
    }
}

// pack 8 fp32 -> short8 of bf16 (RNE via __float2bfloat16)
__device__ __forceinline__ short8 cvt8(float4 a, float4 b) {
    union { short8 v; __hip_bfloat16 h[8]; } u;
    u.h[0] = __float2bfloat16(a.x); u.h[1] = __float2bfloat16(a.y);
    u.h[2] = __float2bfloat16(a.z); u.h[3] = __float2bfloat16(a.w);
    u.h[4] = __float2bfloat16(b.x); u.h[5] = __float2bfloat16(b.y);
    u.h[6] = __float2bfloat16(b.z); u.h[7] = __float2bfloat16(b.w);
    return u.v;
}

__device__ __forceinline__ uint4 s8u4(short8 v) {
    union { short8 s; uint4 u; } x; x.s = v; return x.u;
}

// ---------------------------------------------------------------------------
// Kernel 1 (v6): y = adj @ X^T, bf16 MFMA 16x16x32, 2 kernels total now.
// KSEG=8: block covers 128 rows x 512 k via TWO sequential 48 KB LDS stages
// of X (256 k each), fp32->bf16 converted DURING staging (cvt_x deleted).
// Inner loop unchanged from validated v4/v5: barrier-free, adj global->reg
// 2-deep static prefetch, X from XOR-swizzled LDS (slot = c ^ (r&7),
// conflict-free ds_read_b128). 3 barriers total per block.
// Partial stores col-major (yws[slice][col][row]) -> float4 per acc[ct].
// Grid 96 rowgroups x 8 ksegs = 768 blocks x 512 thr; 48 KB LDS.
// C/D mapping P0 (HW-validated): col=lane&15, row=(lane>>4)*4+reg.
// ---------------------------------------------------------------------------
__global__ __launch_bounds__(512, 4) void gemm_y(
    const void* __restrict__ adjv, const void* __restrict__ xv,
    float* __restrict__ yws)
{
    __shared__ uint4 Xs[96 * 32];   // 48 KB, swizzled 16B chunks (256 k)

    const int tid = threadIdx.x;
    const int isf32 = probe32(adjv);
    const int wv = tid >> 6, ln = tid & 63, fr = ln & 15, fq = ln >> 4;

    const int bid = blockIdx.x;
    const int rt0 = (bid >> 3) * 128;   // 128 rows per block (8 waves x 16)
    const int ks  = bid & 7;
    const int k0  = ks * KLEN;

    float4v acc[6];
#pragma unroll
    for (int i = 0; i < 6; i++) acc[i] = (float4v){0.f, 0.f, 0.f, 0.f};

    const int arow = rt0 + wv * 16 + fr;   // this lane's adj row

    // stage-chunk geometry: 96 rows x 32 chunks of 16B; 6 chunks/thread
    const int sL0 = tid;                    // + s*512
#define XFRAG(CT, STEP) \
    (*(const short8*)&Xs[((CT) * 16 + fr) * 32 + ((((STEP) * 4) + fq) ^ (((CT) * 16 + fr) & 7))])

#define STAGEF(HK) { _Pragma("unroll")                                         \
    for (int s = 0; s < 6; s++) {                                              \
        int L = sL0 + s * 512; int r = L >> 5, c = L & 31;                     \
        const float* p = (const float*)xv + (size_t)r * NNODES + (HK) + c * 8; \
        Xs[r * 32 + (c ^ (r & 7))] =                                           \
            s8u4(cvt8(*(const float4*)p, *(const float4*)(p + 4)));            \
    } }
#define STAGEB(HK) { _Pragma("unroll")                                         \
    for (int s = 0; s < 6; s++) {                                              \
        int L = sL0 + s * 512; int r = L >> 5, c = L & 31;                     \
        Xs[r * 32 + (c ^ (r & 7))] = *(const uint4*)(                          \
            (const __hip_bfloat16*)xv + (size_t)r * NNODES + (HK) + c * 8);    \
    } }

    if (isf32) {
        const float* ap = (const float*)adjv + (size_t)arow * NNODES + k0 + fq * 8;
        float4 AA[2], AB[2];

#define ALOADF(R, STEP) { const float* p = ap + (STEP) * 32;                   \
        R[0] = *(const float4*)p; R[1] = *(const float4*)(p + 4); }
#define COMPF(R, STEP) { short8 a = cvt8(R[0], R[1]);                          \
        _Pragma("unroll")                                                      \
        for (int ct = 0; ct < 6; ct++)                                         \
            acc[ct] = __builtin_amdgcn_mfma_f32_16x16x32_bf16(a, XFRAG(ct, (STEP) & 7), acc[ct], 0, 0, 0); }

        STAGEF(k0);
        ALOADF(AA, 0); ALOADF(AB, 1);
        __syncthreads();                 // stage 0 visible
        COMPF(AA, 0);  ALOADF(AA, 2);
        COMPF(AB, 1);  ALOADF(AB, 3);
        COMPF(AA, 2);  ALOADF(AA, 4);
        COMPF(AB, 3);  ALOADF(AB, 5);
        COMPF(AA, 4);  ALOADF(AA, 6);
        COMPF(AB, 5);  ALOADF(AB, 7);
        COMPF(AA, 6);  ALOADF(AA, 8);    // prefetch first adj of half 1
        COMPF(AB, 7);  ALOADF(AB, 9);
        __syncthreads();                 // all readers done with stage 0
        STAGEF(k0 + 256);
        __syncthreads();                 // stage 1 visible
        COMPF(AA, 8);   ALOADF(AA, 10);
        COMPF(AB, 9);   ALOADF(AB, 11);
        COMPF(AA, 10);  ALOADF(AA, 12);
        COMPF(AB, 11);  ALOADF(AB, 13);
        COMPF(AA, 12);  ALOADF(AA, 14);
        COMPF(AB, 13);  ALOADF(AB, 15);
        COMPF(AA, 14);
        COMPF(AB, 15);
#undef ALOADF
#undef COMPF
    } else {
        // bf16 input path (insurance)
        const __hip_bfloat16* ap = (const __hip_bfloat16*)adjv + (size_t)arow * NNODES + k0 + fq * 8;
        uint4 AA, AB;

#define ALOADB(R, STEP) R = *(const uint4*)(ap + (STEP) * 32);
#define COMPB(R, STEP) { short8 a = *(const short8*)&R;                        \
        _Pragma("unroll")                                                      \
        for (int ct = 0; ct < 6; ct++)                                         \
            acc[ct] = __builtin_amdgcn_mfma_f32_16x16x32_bf16(a, XFRAG(ct, (STEP) & 7), acc[ct], 0, 0, 0); }

        STAGEB(k0);
        ALOADB(AA, 0); ALOADB(AB, 1);
        __syncthreads();
        COMPB(AA, 0);  ALOADB(AA, 2);
        COMPB(AB, 1);  ALOADB(AB, 3);
        COMPB(AA, 2);  ALOADB(AA, 4);
        COMPB(AB, 3);  ALOADB(AB, 5);
        COMPB(AA, 4);  ALOADB(AA, 6);
        COMPB(AB, 5);  ALOADB(AB, 7);
        COMPB(AA, 6);  ALOADB(AA, 8);
        COMPB(AB, 7);  ALOADB(AB, 9);
        __syncthreads();
        STAGEB(k0 + 256);
        __syncthreads();
        COMPB(AA, 8);   ALOADB(AA, 10);
        COMPB(AB, 9);   ALOADB(AB, 11);
        COMPB(AA, 10);  ALOADB(AA, 12);
        COMPB(AB, 11);  ALOADB(AB, 13);
        COMPB(AA, 12);  ALOADB(AA, 14);
        COMPB(AB, 13);  ALOADB(AB, 15);
        COMPB(AA, 14);
        COMPB(AB, 15);
#undef ALOADB
#undef COMPB
    }
#undef XFRAG
#undef STAGEF
#undef STAGEB

    // store partials: slice ks, COL-MAJOR yws[slice][col][row] -> float4/acc
    float* yo = yws + (size_t)ks * YSLICE;
    const int rowb = rt0 + wv * 16 + fq * 4;
#pragma unroll
    for (int ct = 0; ct < 6; ct++) {
        float4 v; v.x = acc[ct][0]; v.y = acc[ct][1]; v.z = acc[ct][2]; v.w = acc[ct][3];
        *(float4*)(yo + (size_t)(ct * 16 + fr) * NROWS + rowb) = v;
    }
}

// ---------------------------------------------------------------------------
// Kernel 2: epilogue. 4 lanes (a quad) per (b,n): each lane owns 3 t's of the
// cheb/sgc sum, quad-reduced via shfl_xor; GLU o-range split across the quad.
// Sums the 8 col-major partial slices directly (L3-resident; reduce_y
// deleted). gw LDS row stride padded 768->780 floats: 195 chunks/row, 195%8=3
// spreads the 4 tq-groups across bank-quads (was 4-way same-bank).
// 512 blocks x 256 thr.
// ---------------------------------------------------------------------------
__global__ __launch_bounds__(256) void epilogue_kernel(
    const void* __restrict__ xv, const float* __restrict__ yws,
    const void* __restrict__ chebv, const void* __restrict__ gcnwv,
    const void* __restrict__ gcnbv, const void* __restrict__ g1wv,
    const void* __restrict__ g1bv, const void* __restrict__ g2wv,
    const void* __restrict__ g2bv,
    float* __restrict__ out, const void* __restrict__ adjp)
{
    __shared__ __align__(16) float gwL[12 * 780];   // [t][j*12+o], padded
    __shared__ __align__(16) float cw4L[256];       // [j*4+k], padded to float4
    __shared__ float w1L[216];    // [o*18 + c*3 + kh]  (kw=1 tap)
    __shared__ float w2L[216];
    __shared__ float wbL[36];

    const int tid = threadIdx.x;
    const int isf32 = probe32(adjp);

    for (int i = tid; i < 9216; i += 256) {
        int o = i / 768, t = (i / 64) % 12, j = i % 64;   // gcn_w flat (o,t,0,j)
        gwL[t * 780 + j * 12 + o] = ldf(gcnwv, i, isf32);
    }
    {
        int j = tid >> 2, kk = tid & 3;
        cw4L[tid] = (kk < 3 && j < 64) ? ldf(chebv, j * 3 + kk, isf32) : 0.f;
    }
    if (tid < 216) {
        w1L[tid] = ldf(g1wv, (size_t)tid * 3 + 1, isf32);
        w2L[tid] = ldf(g2wv, (size_t)tid * 3 + 1, isf32);
    }
    if (tid < 12) {
        wbL[tid]      = ldf(gcnbv, tid, isf32);
        wbL[12 + tid] = ldf(g1bv, tid, isf32);
        wbL[24 + tid] = ldf(g2bv, tid, isf32);
    }
    __syncthreads();

    const int gid = blockIdx.x * 256 + tid;   // 0..131071
    const int pr  = gid >> 2;                 // (b,n) pair 0..32767
    const int tq  = gid & 3;                  // t-quarter 0..3
    const int b = pr >> 12;
    const int n = pr & (NNODES - 1);

    // y values for this lane's 3 t's: sum 8 col-major slices
    // addr = sl*YSLICE + (b*12 + tq*3 + i)*NROWS + k*4096 + n
    float yk[3][3];
#pragma unroll
    for (int k = 0; k < 3; k++) { yk[k][0] = 0.f; yk[k][1] = 0.f; yk[k][2] = 0.f; }
#pragma unroll
    for (int sl = 0; sl < KSEG; sl++) {
        const float* base = yws + (size_t)sl * YSLICE
                          + (size_t)(b * 12 + tq * 3) * NROWS + n;
#pragma unroll
        for (int i = 0; i < 3; i++)
#pragma unroll
            for (int k = 0; k < 3; k++)
                yk[k][i] += base[(size_t)i * NROWS + k * NNODES];
    }

    // ---- cheb -> relu -> partial sgc over 3 t's ----
    float sg[12];
#pragma unroll
    for (int o = 0; o < 12; o++) sg[o] = 0.f;
    const float4* cw4 = (const float4*)cw4L;
#pragma unroll
    for (int i = 0; i < 3; i++) {
        const float y0 = yk[0][i], y1 = yk[1][i], y2 = yk[2][i];
        const float4* gw4 = (const float4*)(gwL + (tq * 3 + i) * 780);
#pragma unroll 4
        for (int j = 0; j < 64; j++) {
            float4 cw = cw4[j];
            float h = fmaf(y0, cw.x, fmaf(y1, cw.y, y2 * cw.z));
            h = fmaxf(h, 0.f);
            float4 g0 = gw4[j * 3], g1 = gw4[j * 3 + 1], g2 = gw4[j * 3 + 2];
            sg[0] += h * g0.x; sg[1] += h * g0.y; sg[2]  += h * g0.z; sg[3]  += h * g0.w;
            sg[4] += h * g1.x; sg[5] += h * g1.y; sg[6]  += h * g1.z; sg[7]  += h * g1.w;
            sg[8] += h * g2.x; sg[9] += h * g2.y; sg[10] += h * g2.z; sg[11] += h * g2.w;
        }
    }
    // quad reduction: all 4 lanes end with the full t-sum
#pragma unroll
    for (int o = 0; o < 12; o++) {
        sg[o] += __shfl_xor(sg[o], 1);
        sg[o] += __shfl_xor(sg[o], 2);
    }

    // ---- GLU (dilated conv taps n-2, n, n+2; only kw=1 alive); this lane
    // handles o = tq*3 .. tq*3+2 ----
    float xa[18], xg[18];
#pragma unroll
    for (int c = 0; c < 6; c++)
#pragma unroll
        for (int kh = 0; kh < 3; kh++) {
            int m = n + 2 * kh - 2;
            bool ok = ((unsigned)m < (unsigned)NNODES);
            xa[c * 3 + kh] = ok ? ldf(xv, ((size_t)(b * 12 + c)) * NNODES + m, isf32) : 0.f;
            xg[c * 3 + kh] = ok ? ldf(xv, ((size_t)(b * 12 + c + 6)) * NNODES + m, isf32) : 0.f;
        }

#pragma unroll
    for (int i = 0; i < 3; i++) {
        const int o = tq * 3 + i;
        float av = wbL[12 + o], gv = wbL[24 + o];
#pragma unroll
        for (int q = 0; q < 18; q++) {
            av += xa[q] * w1L[o * 18 + q];
            gv += xg[q] * w2L[o * 18 + q];
        }
        float s = 1.f / (1.f + expf(-gv));
        out[((size_t)(b * 12 + o)) * NNODES + n] = av * s + sg[o] + wbL[o];
    }
}

// ---------------------------------------------------------------------------
// Fallback single kernel (only if ws too small): verified path.
// ---------------------------------------------------------------------------
__global__ __launch_bounds__(64) void fused_simple(
    const void* __restrict__ xv, const void* __restrict__ adjv,
    const void* __restrict__ chebv, const void* __restrict__ gcnwv,
    const void* __restrict__ gcnbv, const void* __restrict__ g1wv,
    const void* __restrict__ g1bv, const void* __restrict__ g2wv,
    const void* __restrict__ g2bv,
    float* __restrict__ out)
{
    __shared__ float gwL[9216];
    __shared__ float cwL[192];
    __shared__ float w1L[216];
    __shared__ float w2L[216];
    __shared__ float wbL[36];

    const int tid = threadIdx.x;
    const int isf32 = probe32(adjv);

    for (int i = tid; i < 9216; i += 64) {
        int o = i / 768, t = (i / 64) % 12, j = i % 64;
        gwL[t * 768 + j * 12 + o] = ldf(gcnwv, i, isf32);
    }
    for (int i = tid; i < 192; i += 64) cwL[i] = ldf(chebv, i, isf32);
    for (int i = tid; i < 216; i += 64) {
        w1L[i] = ldf(g1wv, (size_t)i * 3 + 1, isf32);
        w2L[i] = ldf(g2wv, (size_t)i * 3 + 1, isf32);
    }
    if (tid < 12) {
        wbL[tid]      = ldf(gcnbv, tid, isf32);
        wbL[12 + tid] = ldf(g1bv, tid, isf32);
        wbL[24 + tid] = ldf(g2bv, tid, isf32);
    }
    __syncthreads();

    const int g = blockIdx.x * 64 + tid;
    const int b = g >> 12;
    const int n = g & (NNODES - 1);

    float y[3][12];
#pragma unroll
    for (int k = 0; k < 3; k++)
#pragma unroll
        for (int t = 0; t < 12; t++) y[k][t] = 0.f;

    for (int m0 = 0; m0 < NNODES; m0 += 8) {
        float a0[8], a1[8], a2[8];
        ld8(a0, adjv, ((size_t)(0 * NNODES + n)) * NNODES + m0, isf32);
        ld8(a1, adjv, ((size_t)(1 * NNODES + n)) * NNODES + m0, isf32);
        ld8(a2, adjv, ((size_t)(2 * NNODES + n)) * NNODES + m0, isf32);
#pragma unroll
        for (int t = 0; t < 12; t++) {
            float x8[8];
            ld8(x8, xv, ((size_t)(b * 12 + t)) * NNODES + m0, isf32);
#pragma unroll
            for (int j = 0; j < 8; j++) {
                y[0][t] += a0[j] * x8[j];
                y[1][t] += a1[j] * x8[j];
                y[2][t] += a2[j] * x8[j];
            }
        }
    }

    float sg[12];
#pragma unroll
    for (int o = 0; o < 12; o++) sg[o] = wbL[o];
    for (int t = 0; t < 12; t++) {
        const float y0 = y[0][t], y1 = y[1][t], y2 = y[2][t];
        const float* gwt = gwL + t * 768;
#pragma unroll 4
        for (int j = 0; j < 64; j++) {
            float h = y0 * cwL[j * 3] + y1 * cwL[j * 3 + 1] + y2 * cwL[j * 3 + 2];
            h = fmaxf(h, 0.f);
#pragma unroll
            for (int o = 0; o < 12; o++) sg[o] += h * gwt[j * 12 + o];
        }
    }

    float xa[18], xg[18];
#pragma unroll
    for (int c = 0; c < 6; c++)
#pragma unroll
        for (int kh = 0; kh < 3; kh++) {
            int m = n + 2 * kh - 2;
            bool ok = ((unsigned)m < (unsigned)NNODES);
            xa[c * 3 + kh] = ok ? ldf(xv, ((size_t)(b * 12 + c)) * NNODES + m, isf32) : 0.f;
            xg[c * 3 + kh] = ok ? ldf(xv, ((size_t)(b * 12 + c + 6)) * NNODES + m, isf32) : 0.f;
        }

#pragma unroll
    for (int o = 0; o < 12; o++) {
        float av = wbL[12 + o], gv = wbL[24 + o];
#pragma unroll
        for (int i = 0; i < 18; i++) {
            av += xa[i] * w1L[o * 18 + i];
            gv += xg[i] * w2L[o * 18 + i];
        }
        float s = 1.f / (1.f + expf(-gv));
        out[((size_t)(b * 12 + o)) * NNODES + n] = av * s + sg[o];
    }
}

// ---------------------------------------------------------------------------
extern "C" void kernel_launch(void* const* d_in, const int* in_sizes, int n_in,
                              void* d_out, int out_size, void* d_ws, size_t ws_size,
                              hipStream_t stream)
{
    float* yws = (float*)((char*)d_ws + 64);   // 8 col-major slices, 37.7 MB
    const size_t need = 64 + (size_t)KSEG * YSLICE * 4;

    if (ws_size >= need) {
        hipLaunchKernelGGL(gemm_y, dim3(96 * KSEG), dim3(512), 0, stream,
                           d_in[1], d_in[0], yws);
        hipLaunchKernelGGL(epilogue_kernel, dim3(512), dim3(256), 0, stream,
                           d_in[0], yws, d_in[2], d_in[3], d_in[4],
                           d_in[5], d_in[6], d_in[7], d_in[8],
                           (float*)d_out, d_in[1]);
    } else {
        hipLaunchKernelGGL(fused_simple, dim3(512), dim3(64), 0, stream,
                           d_in[0], d_in[1], d_in[2], d_in[3], d_in[4],
                           d_in[5], d_in[6], d_in[7], d_in[8],
                           (float*)d_out);
    }
}